// Round 11
// baseline (325.732 us; speedup 1.0000x reference)
//
#include <hip/hip_runtime.h>
#include <hip/hip_bf16.h>
#include <stdint.h>

// out[M,N] = x[M,K] @ weight[N,K]^T ; M=8192, N=4096, K=4096, fp32 in/out.
// Pass 1: fp32 -> bf16 convert (memory-bound) into d_ws.
// Pass 2: 256x256 8-wave 8-phase bf16 MFMA GEMM, round-5 schedule (single
//   end-of-phase barrier, counted lgkmcnt, vmcnt(4)@P4/P8, T1 XCD swizzle,
//   T5 setprio), upgraded to 32x32x16 MFMA (2495 vs 2075 TF ceiling).
// Round 11: slot-major LDS chunks kill round-3's 4-way conflicts:
//   each 8-row x 64-k chunk (1024B) stored [slot 0..7][row 0..7] x 16B.
//   Staging: lane l -> global row (l&7), k-slot (l>>3) (global addr is
//   per-lane-free; LDS write stays linear base+l*16). Fragment read:
//   byte = mblk*4096 + ks*256 + abase, abase=(l31>>3)*1024+(l>>5)*128+
//   (l31&7)*16 -> every 8-lane group covers all 32 banks once =
//   conflict-free. Operand/C-D mappings validated by round-3 pass.
//   ILP: 8 MFMA/phase split by ks-pair = 4 indep chains depth 2.
// Schedule (= round 5; WAR/RAW audit identical):
//   P1: rd fa[0,1]ks01+fb[0,1]ks01 | st A11@kA | MQ32(0,0)
//   P2: rd fa[0,1]ks23+fb[0,1]ks23 | st B11@kA | MQ32(0,2)
//   P3: rd fa[2,3]ks0..3           | st B00@kB | MQ32(2,0)
//   P4: -                          | st A00@kB | MQ32(2,2) VM4
//   P5-P8: buf1 mirror (st A01,B01,B10,A10), VM4@P8.

typedef __bf16 bf16x8 __attribute__((ext_vector_type(8)));
typedef float f32x4 __attribute__((ext_vector_type(4)));
typedef float f32x16 __attribute__((ext_vector_type(16)));

__device__ __forceinline__ unsigned short f2bf(float f) {
  unsigned u = __builtin_bit_cast(unsigned, f);
  u += 0x7FFFu + ((u >> 16) & 1u);  // RNE; Gaussian inputs, no NaN
  return (unsigned short)(u >> 16);
}

__global__ void cvt_f32_to_bf16(const float* __restrict__ src,
                                unsigned short* __restrict__ dst, long n4) {
  long i = (long)blockIdx.x * blockDim.x + threadIdx.x;
  const long stride = (long)gridDim.x * blockDim.x;
  for (; i < n4; i += stride) {
    float4 v = reinterpret_cast<const float4*>(src)[i];
    ushort4 o;
    o.x = f2bf(v.x); o.y = f2bf(v.y); o.z = f2bf(v.z); o.w = f2bf(v.w);
    reinterpret_cast<ushort4*>(dst)[i] = o;
  }
}

__device__ __forceinline__ void gload_lds16(const void* g, void* lds) {
  // async global->LDS, 16B/lane; LDS dest = wave-uniform base + lane*16
  __builtin_amdgcn_global_load_lds(
      (__attribute__((address_space(1))) void*)(g),
      (__attribute__((address_space(3))) void*)(lds), 16, 0, 0);
}

#define BARRIER()                                    \
  do {                                               \
    asm volatile("" ::: "memory");                   \
    __builtin_amdgcn_s_barrier();                    \
    asm volatile("" ::: "memory");                   \
  } while (0)
#define WAIT_VM4() asm volatile("s_waitcnt vmcnt(4)" ::: "memory")
#define WAIT_VM0() asm volatile("s_waitcnt vmcnt(0)" ::: "memory")

// ---- fragment reads: slot-major chunks, compile-time offsets ----
#define RDA(AB, MI, KS)                                                      \
  fa[MI][KS] = *(const bf16x8*)((AB) + (MI)*4096 + (KS)*256 + abase);
#define RDB(BB, NI, KS)                                                      \
  fb[NI][KS] = *(const bf16x8*)((BB) + (NI)*4096 + (KS)*256 + bbase);
#define READ_P1(AB, BB)                                                      \
  RDA(AB, 0, 0) RDA(AB, 0, 1) RDA(AB, 1, 0) RDA(AB, 1, 1)                    \
  RDB(BB, 0, 0) RDB(BB, 0, 1) RDB(BB, 1, 0) RDB(BB, 1, 1)
#define READ_P2(AB, BB)                                                      \
  RDA(AB, 0, 2) RDA(AB, 0, 3) RDA(AB, 1, 2) RDA(AB, 1, 3)                    \
  RDB(BB, 0, 2) RDB(BB, 0, 3) RDB(BB, 1, 2) RDB(BB, 1, 3)
#define READ_P3(AB)                                                          \
  RDA(AB, 2, 0) RDA(AB, 2, 1) RDA(AB, 2, 2) RDA(AB, 2, 3)                    \
  RDA(AB, 3, 0) RDA(AB, 3, 1) RDA(AB, 3, 2) RDA(AB, 3, 3)
// 8 MFMA: mi-pair M0 x both n x ks-pair K0; 4 indep chains depth 2
#define MQ32(M0, K0)                                                         \
  _Pragma("unroll") for (int kx = 0; kx < 2; ++kx)                           \
  _Pragma("unroll") for (int mi = 0; mi < 2; ++mi)                           \
  _Pragma("unroll") for (int ni = 0; ni < 2; ++ni)                           \
      acc[(M0) + mi][ni] = __builtin_amdgcn_mfma_f32_32x32x16_bf16(          \
          fa[(M0) + mi][(K0) + kx], fb[ni][(K0) + kx], acc[(M0) + mi][ni],   \
          0, 0, 0);

// phase: {reads || stage} -> prio1 MFMA prio0 -> [vm] -> barrier
#define PH(READS, STAGES, MQS, WAITS)     \
  do {                                    \
    READS STAGES                          \
    __builtin_amdgcn_s_setprio(1);        \
    MQS                                   \
    __builtin_amdgcn_s_setprio(0);        \
    WAITS BARRIER();                      \
  } while (0)

__global__ __launch_bounds__(512, 2) void gemm256(
    const unsigned short* __restrict__ A, const unsigned short* __restrict__ B,
    float* __restrict__ C, int M, int N, int K) {
  // LDS: A halves at (buf*2+h)*16384 ; B at 65536 + (buf*2+h)*16384
  __shared__ __attribute__((aligned(1024))) char lds[131072];
  const int A00 = 0, A01 = 16384, A10 = 32768, A11 = 49152;
  const int B00 = 65536, B01 = 81920, B10 = 98304, B11 = 114688;

  const int t = threadIdx.x;
  const int l = t & 63;
  const int w = t >> 6;        // wave 0..7
  const int wm = w >> 2;       // 0..1 : 128-row half of the 256-row tile
  const int wn = w & 3;        // 0..3 : 64-col strip of the 256-col tile
  const int l31 = l & 31;
  // slot-major read bases (bytes): chunk(row>>3)*1024 + slot*128 + row&7*16
  const int abase = (l31 >> 3) * 1024 + (l >> 5) * 128 + (l31 & 7) * 16;
  const int bbase = (wn & 1) * 8192 + abase;
  const int srow = l & 7;        // staging: global row within 8-row chunk
  const int sslot = (l >> 3) * 8;  // staging: global k-slot (8 elems)

  // T1: bijective XCD swizzle (nwg % 8 == 0 here)
  const int nwg = gridDim.x;
  int swz = blockIdx.x;
  if ((nwg & 7) == 0) swz = (swz & 7) * (nwg >> 3) + (swz >> 3);
  const int ntx = N >> 8;
  const int bx = swz % ntx;
  const int by = swz / ntx;
  const int mBase = by * 256, nBase = bx * 256;

  // read bases: wave's A half per buffer, B half per buffer
  const char* Ard0 = lds + wm * 16384;
  const char* Ard1 = lds + 32768 + wm * 16384;
  const char* Brd0 = lds + 65536 + (wn >> 1) * 16384;
  const char* Brd1 = lds + 98304 + (wn >> 1) * 16384;

  bf16x8 fa[4][4], fb[2][4];   // fa[mblk][ks], fb[nblk][ks]
  f32x16 acc[4][2] = {};

  auto STAGE = [&](const unsigned short* __restrict__ G, int row0, int k0,
                   int ldsOff) {
    const unsigned short* s =
        G + (size_t)(row0 + w * 8 + srow) * K + k0 + sslot;
    char* d = lds + ldsOff + w * 1024;
    gload_lds16(s, d);                          // rows 0-63 of the half
    gload_lds16(s + (size_t)64 * K, d + 8192);  // rows 64-127
  };

  // ---- prologue: tile0 (4 halves) + B10,A10 of tile1; drain tile0 ----
  STAGE(A, mBase, 0, A00);
  STAGE(A, mBase + 128, 0, A01);
  STAGE(B, nBase, 0, B00);
  STAGE(B, nBase + 128, 0, B01);
  STAGE(B, nBase, 64, B10);
  STAGE(A, mBase, 64, A10);
  WAIT_VM4();
  BARRIER();

  // ---- main loop: iteration i computes tiles 2i (buf0), 2i+1 (buf1) ----
  const int itermain = K / 128 - 1;
  for (int i = 0; i < itermain; ++i) {
    const int kA = (2 * i + 1) * 64;  // tile 2i+1
    const int kB = kA + 64;           // tile 2i+2
    const int kC = kB + 64;           // tile 2i+3
    PH(READ_P1(Ard0, Brd0), STAGE(A, mBase + 128, kA, A11);, MQ32(0, 0), );
    PH(READ_P2(Ard0, Brd0), STAGE(B, nBase + 128, kA, B11);, MQ32(0, 2), );
    PH(READ_P3(Ard0),       STAGE(B, nBase,       kB, B00);, MQ32(2, 0), );
    PH(,                    STAGE(A, mBase,       kB, A00);, MQ32(2, 2), WAIT_VM4(););
    PH(READ_P1(Ard1, Brd1), STAGE(A, mBase + 128, kB, A01);, MQ32(0, 0), );
    PH(READ_P2(Ard1, Brd1), STAGE(B, nBase + 128, kB, B01);, MQ32(0, 2), );
    PH(READ_P3(Ard1),       STAGE(B, nBase,       kC, B10);, MQ32(2, 0), );
    PH(,                    STAGE(A, mBase,       kC, A10);, MQ32(2, 2), WAIT_VM4(););
  }

  // ---- tail: tiles nt-2 (buf0), nt-1 (buf1) ----
  {
    const int kT = K - 64;  // last tile
    PH(READ_P1(Ard0, Brd0), STAGE(A, mBase + 128, kT, A11);, MQ32(0, 0), );
    PH(READ_P2(Ard0, Brd0), STAGE(B, nBase + 128, kT, B11);, MQ32(0, 2), );
    PH(READ_P3(Ard0),       ,                                MQ32(2, 0), );
    PH(,                    ,                                MQ32(2, 2), WAIT_VM0(););
    PH(READ_P1(Ard1, Brd1), ,                                MQ32(0, 0), );
    PH(READ_P2(Ard1, Brd1), ,                                MQ32(0, 2), );
    PH(READ_P3(Ard1),       ,                                MQ32(2, 0), );
    // final phase: no barrier needed after
    __builtin_amdgcn_s_setprio(1);
    MQ32(2, 2)
    __builtin_amdgcn_s_setprio(0);
  }

  // ---- epilogue: 32x32 C/D layout (m74/m101, round-3 verified):
  //      col = lane&31, row = (reg&3) + 8*(reg>>2) + 4*(lane>>5) ----
  const int cl = l & 31, ch = l >> 5;
  float* Cw = C + (size_t)(mBase + wm * 128 + 4 * ch) * N + nBase + wn * 64 + cl;
#pragma unroll
  for (int mi = 0; mi < 4; ++mi)
#pragma unroll
    for (int ni = 0; ni < 2; ++ni)
#pragma unroll
      for (int r = 0; r < 16; ++r)
        Cw[(size_t)(mi * 32 + (r & 3) + 8 * (r >> 2)) * N + ni * 32] =
            acc[mi][ni][r];
}

// ---- fallback (round-1 verified fused path; used only if ws too small) ----
typedef unsigned short ushort8f __attribute__((ext_vector_type(8)));
__global__ __launch_bounds__(256) void gemm_fb(
    const float* __restrict__ Af, const float* __restrict__ Wf,
    float* __restrict__ C, int M, int N, int K) {
  __shared__ __attribute__((aligned(16))) unsigned short Ash[128 * 64];
  __shared__ __attribute__((aligned(16))) unsigned short Bsh[128 * 64];
  const int t = threadIdx.x, l = t & 63, w = t >> 6;
  const int mBase = blockIdx.y * 128, nBase = blockIdx.x * 128;
  const int wm = w >> 1, wn = w & 1;
  const int lr = l & 15, lk = (l >> 4) * 8;
  f32x4 acc[4][4] = {};
  const int frow = t >> 1, fkh = (t & 1) * 32;
  for (int k0 = 0; k0 < K; k0 += 64) {
    const float* ga = Af + (size_t)(mBase + frow) * K + k0 + fkh;
    const float* gb = Wf + (size_t)(nBase + frow) * K + k0 + fkh;
#pragma unroll
    for (int j = 0; j < 4; ++j) {
      float4 a0 = reinterpret_cast<const float4*>(ga)[2 * j];
      float4 a1 = reinterpret_cast<const float4*>(ga)[2 * j + 1];
      float4 b0 = reinterpret_cast<const float4*>(gb)[2 * j];
      float4 b1 = reinterpret_cast<const float4*>(gb)[2 * j + 1];
      ushort8f oa = {f2bf(a0.x), f2bf(a0.y), f2bf(a0.z), f2bf(a0.w),
                     f2bf(a1.x), f2bf(a1.y), f2bf(a1.z), f2bf(a1.w)};
      ushort8f ob = {f2bf(b0.x), f2bf(b0.y), f2bf(b0.z), f2bf(b0.w),
                     f2bf(b1.x), f2bf(b1.y), f2bf(b1.z), f2bf(b1.w)};
      *reinterpret_cast<ushort8f*>(&Ash[frow * 64 + fkh + j * 8]) = oa;
      *reinterpret_cast<ushort8f*>(&Bsh[frow * 64 + fkh + j * 8]) = ob;
    }
    __syncthreads();
#pragma unroll
    for (int kk = 0; kk < 2; ++kk) {
      bf16x8 a[4], b[4];
#pragma unroll
      for (int mi = 0; mi < 4; ++mi)
        a[mi] = *reinterpret_cast<const bf16x8*>(
            &Ash[(wm * 64 + mi * 16 + lr) * 64 + kk * 32 + lk]);
#pragma unroll
      for (int ni = 0; ni < 4; ++ni)
        b[ni] = *reinterpret_cast<const bf16x8*>(
            &Bsh[(wn * 64 + ni * 16 + lr) * 64 + kk * 32 + lk]);
#pragma unroll
      for (int mi = 0; mi < 4; ++mi)
#pragma unroll
        for (int ni = 0; ni < 4; ++ni)
          acc[mi][ni] = __builtin_amdgcn_mfma_f32_16x16x32_bf16(
              a[mi], b[ni], acc[mi][ni], 0, 0, 0);
    }
    __syncthreads();
  }
  const int crow0 = mBase + wm * 64 + (l >> 4) * 4;
  const int ccol0 = nBase + wn * 64 + lr;
#pragma unroll
  for (int mi = 0; mi < 4; ++mi)
#pragma unroll
    for (int ni = 0; ni < 4; ++ni)
#pragma unroll
      for (int r = 0; r < 4; ++r)
        C[(size_t)(crow0 + mi * 16 + r) * N + ccol0 + ni * 16] =
            acc[mi][ni][r];
}

extern "C" void kernel_launch(void* const* d_in, const int* in_sizes, int n_in,
                              void* d_out, int out_size, void* d_ws, size_t ws_size,
                              hipStream_t stream) {
  (void)n_in; (void)out_size;
  const float* x = (const float*)d_in[0];
  const float* wgt = (const float*)d_in[1];
  float* out = (float*)d_out;

  const long x_elems = in_sizes[0];  // M*K
  const long w_elems = in_sizes[1];  // N*K
  const int K = 4096;
  const int M = (int)(x_elems / K);  // 8192
  const int N = (int)(w_elems / K);  // 4096

  const size_t need = (size_t)(x_elems + w_elems) * sizeof(unsigned short);
  const bool ok256 =
      (M % 256 == 0) && (N % 256 == 0) && (K % 128 == 0) && (K >= 256) &&
      ws_size >= need;
  if (ok256) {
    unsigned short* Abf = (unsigned short*)d_ws;
    unsigned short* Wbf = Abf + x_elems;
    cvt_f32_to_bf16<<<2048, 256, 0, stream>>>(x, Abf, x_elems / 4);
    cvt_f32_to_bf16<<<2048, 256, 0, stream>>>(wgt, Wbf, w_elems / 4);
    gemm256<<<dim3((M / 256) * (N / 256)), 512, 0, stream>>>(Abf, Wbf, out, M,
                                                             N, K);
  } else {
    dim3 grid(N / 128, M / 128);
    gemm_fb<<<grid, 256, 0, stream>>>(x, wgt, out, M, N, K);
  }
}

// Round 12
// 288.189 us; speedup vs baseline: 1.1303x; 1.1303x over previous
//
#include <hip/hip_runtime.h>
#include <hip/hip_bf16.h>
#include <stdint.h>

// out[M,N] = x[M,K] @ weight[N,K]^T ; M=8192, N=4096, K=4096, fp32 in/out.
// Pass 1: fp32 -> bf16 convert (memory-bound) into d_ws.
// Pass 2: 256x256 8-wave 8-phase bf16 32x32x16-MFMA GEMM, round-5 schedule.
// Round 12: bank-quad-safe LDS permutation for the 32x32 operand map.
//   Diagnosis: rounds 3/11 both showed EXACTLY 2.517e7 conflicts; modeling
//   crossbar lane-groups as {l,l+16,l+32,l+48} quads explains r3/r5/r11.
//   The 32x32 lane map (row=l&31, kh=l>>5) puts row-bit4 & kh in the quad;
//   the 16B-slot index must therefore mix them into the bank bits:
//     slot(row,ks,kh) = (row&7) ^ ((row>>4)&1) ^ (kh<<1) ^ (ks&1) ^ ((ks>>1)<<2)
//   -> 8-lane runs: 8 distinct quads; quads {R4,kh}: 4 distinct; 16-runs:
//   2/quad (free, m136); bijective per row. Conflict-free under ALL
//   grouping models. Staging inverts the permutation in the GLOBAL source
//   (linear LDS dest, rule #21): kc=(l&7)^(l>>3)^R4c,
//   koff=16*kc0+8*kc1+32*kc2, R4c=(w>>1)&1 (same for both 64-row instrs).
//   Read: byte = mblk*4096 + abase ^ skx(ks), abase = l31*128 +
//   ((l31&7)^((l31>>4)&1)^((l>>5)<<1))*16, skx = (ks&1)*16 + (ks>>1)*64.
// Schedule (= round 5, race-audited): P1 rd fa01/fb ks01 | st A11;
//   P2 rd fa01/fb ks23 | st B11; P3 rd fa23 all | st B00; P4 st A00, VM4;
//   P5-P8 buf1 mirror. Operand/C-D maps validated by rounds 3/11 passes.

typedef __bf16 bf16x8 __attribute__((ext_vector_type(8)));
typedef float f32x4 __attribute__((ext_vector_type(4)));
typedef float f32x16 __attribute__((ext_vector_type(16)));

__device__ __forceinline__ unsigned short f2bf(float f) {
  unsigned u = __builtin_bit_cast(unsigned, f);
  u += 0x7FFFu + ((u >> 16) & 1u);  // RNE; Gaussian inputs, no NaN
  return (unsigned short)(u >> 16);
}

__global__ void cvt_f32_to_bf16(const float* __restrict__ src,
                                unsigned short* __restrict__ dst, long n4) {
  long i = (long)blockIdx.x * blockDim.x + threadIdx.x;
  const long stride = (long)gridDim.x * blockDim.x;
  for (; i < n4; i += stride) {
    float4 v = reinterpret_cast<const float4*>(src)[i];
    ushort4 o;
    o.x = f2bf(v.x); o.y = f2bf(v.y); o.z = f2bf(v.z); o.w = f2bf(v.w);
    reinterpret_cast<ushort4*>(dst)[i] = o;
  }
}

__device__ __forceinline__ void gload_lds16(const void* g, void* lds) {
  // async global->LDS, 16B/lane; LDS dest = wave-uniform base + lane*16
  __builtin_amdgcn_global_load_lds(
      (__attribute__((address_space(1))) void*)(g),
      (__attribute__((address_space(3))) void*)(lds), 16, 0, 0);
}

#define BARRIER()                                    \
  do {                                               \
    asm volatile("" ::: "memory");                   \
    __builtin_amdgcn_s_barrier();                    \
    asm volatile("" ::: "memory");                   \
  } while (0)
#define WAIT_VM4() asm volatile("s_waitcnt vmcnt(4)" ::: "memory")
#define WAIT_VM0() asm volatile("s_waitcnt vmcnt(0)" ::: "memory")

// ---- fragment reads: bank-quad-safe permuted slots ----
// skx(ks) = (ks&1)*16 + ((ks>>1)&1)*64 ; XOR'd onto abase (bits 4,6)
#define SKX(KS) (((KS)&1) * 16 + (((KS) >> 1) & 1) * 64)
#define RDA(AB, MI, KS)                                                      \
  fa[MI][KS] = *(const bf16x8*)((AB) + (MI)*4096 + (abase ^ SKX(KS)));
#define RDB(BB, NI, KS)                                                      \
  fb[NI][KS] =                                                               \
      *(const bf16x8*)((BB) + bhalf + (NI)*4096 + (abase ^ SKX(KS)));
#define READ_P1(AB, BB)                                                      \
  RDA(AB, 0, 0) RDA(AB, 0, 1) RDA(AB, 1, 0) RDA(AB, 1, 1)                    \
  RDB(BB, 0, 0) RDB(BB, 0, 1) RDB(BB, 1, 0) RDB(BB, 1, 1)
#define READ_P2(AB, BB)                                                      \
  RDA(AB, 0, 2) RDA(AB, 0, 3) RDA(AB, 1, 2) RDA(AB, 1, 3)                    \
  RDB(BB, 0, 2) RDB(BB, 0, 3) RDB(BB, 1, 2) RDB(BB, 1, 3)
#define READ_P3(AB)                                                          \
  RDA(AB, 2, 0) RDA(AB, 2, 1) RDA(AB, 2, 2) RDA(AB, 2, 3)                    \
  RDA(AB, 3, 0) RDA(AB, 3, 1) RDA(AB, 3, 2) RDA(AB, 3, 3)
// 8 MFMA: mi-pair M0 x both n x ks-pair K0; 4 indep chains depth 2
#define MQ32(M0, K0)                                                         \
  _Pragma("unroll") for (int kx = 0; kx < 2; ++kx)                           \
  _Pragma("unroll") for (int mi = 0; mi < 2; ++mi)                           \
  _Pragma("unroll") for (int ni = 0; ni < 2; ++ni)                           \
      acc[(M0) + mi][ni] = __builtin_amdgcn_mfma_f32_32x32x16_bf16(          \
          fa[(M0) + mi][(K0) + kx], fb[ni][(K0) + kx], acc[(M0) + mi][ni],   \
          0, 0, 0);

// phase: {reads || stage} -> prio1 MFMA prio0 -> [vm] -> barrier
#define PH(READS, STAGES, MQS, WAITS)     \
  do {                                    \
    READS STAGES                          \
    __builtin_amdgcn_s_setprio(1);        \
    MQS                                   \
    __builtin_amdgcn_s_setprio(0);        \
    WAITS BARRIER();                      \
  } while (0)

__global__ __launch_bounds__(512, 2) void gemm256(
    const unsigned short* __restrict__ A, const unsigned short* __restrict__ B,
    float* __restrict__ C, int M, int N, int K) {
  // LDS: A halves at (buf*2+h)*16384 ; B at 65536 + (buf*2+h)*16384
  __shared__ __attribute__((aligned(1024))) char lds[131072];
  const int A00 = 0, A01 = 16384, A10 = 32768, A11 = 49152;
  const int B00 = 65536, B01 = 81920, B10 = 98304, B11 = 114688;

  const int t = threadIdx.x;
  const int l = t & 63;
  const int w = t >> 6;        // wave 0..7
  const int wm = w >> 2;       // 0..1 : 128-row half of the 256-row tile
  const int wn = w & 3;        // 0..3 : 64-col strip of the 256-col tile
  const int l31 = l & 31;
  // read base: row(l31)*128 + permuted-slot*16 (ks XORs in via SKX)
  const int abase =
      l31 * 128 +
      (((l31 & 7) ^ ((l31 >> 4) & 1) ^ ((l >> 5) << 1)) << 4);
  const int bhalf = (wn & 1) * 8192;  // 64-row offset inside B half
  // staging inverse-permutation: lane l -> row_local l>>3, slot l&7
  const int R4c = (w >> 1) & 1;  // row bit4 of this wave's 8-row chunk
  const int kc = (l & 7) ^ (l >> 3) ^ R4c;
  const int koff = (kc & 1) * 16 + ((kc >> 1) & 1) * 8 + ((kc >> 2) & 1) * 32;
  const int srow = l >> 3;  // global row within 8-row chunk

  // T1: bijective XCD swizzle (nwg % 8 == 0 here)
  const int nwg = gridDim.x;
  int swz = blockIdx.x;
  if ((nwg & 7) == 0) swz = (swz & 7) * (nwg >> 3) + (swz >> 3);
  const int ntx = N >> 8;
  const int bx = swz % ntx;
  const int by = swz / ntx;
  const int mBase = by * 256, nBase = bx * 256;

  // read bases: wave's A half per buffer, B half per buffer
  const char* Ard0 = lds + wm * 16384;
  const char* Ard1 = lds + 32768 + wm * 16384;
  const char* Brd0 = lds + 65536 + (wn >> 1) * 16384;
  const char* Brd1 = lds + 98304 + (wn >> 1) * 16384;

  bf16x8 fa[4][4], fb[2][4];   // fa[mblk][ks], fb[nblk][ks]
  f32x16 acc[4][2] = {};

  auto STAGE = [&](const unsigned short* __restrict__ G, int row0, int k0,
                   int ldsOff) {
    const unsigned short* s =
        G + (size_t)(row0 + w * 8 + srow) * K + k0 + koff;
    char* d = lds + ldsOff + w * 1024;
    gload_lds16(s, d);                          // rows 0-63 of the half
    gload_lds16(s + (size_t)64 * K, d + 8192);  // rows 64-127 (same R4c)
  };

  // ---- prologue: tile0 (4 halves) + B10,A10 of tile1; drain tile0 ----
  STAGE(A, mBase, 0, A00);
  STAGE(A, mBase + 128, 0, A01);
  STAGE(B, nBase, 0, B00);
  STAGE(B, nBase + 128, 0, B01);
  STAGE(B, nBase, 64, B10);
  STAGE(A, mBase, 64, A10);
  WAIT_VM4();
  BARRIER();

  // ---- main loop: iteration i computes tiles 2i (buf0), 2i+1 (buf1) ----
  const int itermain = K / 128 - 1;
  for (int i = 0; i < itermain; ++i) {
    const int kA = (2 * i + 1) * 64;  // tile 2i+1
    const int kB = kA + 64;           // tile 2i+2
    const int kC = kB + 64;           // tile 2i+3
    PH(READ_P1(Ard0, Brd0), STAGE(A, mBase + 128, kA, A11);, MQ32(0, 0), );
    PH(READ_P2(Ard0, Brd0), STAGE(B, nBase + 128, kA, B11);, MQ32(0, 2), );
    PH(READ_P3(Ard0),       STAGE(B, nBase,       kB, B00);, MQ32(2, 0), );
    PH(,                    STAGE(A, mBase,       kB, A00);, MQ32(2, 2), WAIT_VM4(););
    PH(READ_P1(Ard1, Brd1), STAGE(A, mBase + 128, kB, A01);, MQ32(0, 0), );
    PH(READ_P2(Ard1, Brd1), STAGE(B, nBase + 128, kB, B01);, MQ32(0, 2), );
    PH(READ_P3(Ard1),       STAGE(B, nBase,       kC, B10);, MQ32(2, 0), );
    PH(,                    STAGE(A, mBase,       kC, A10);, MQ32(2, 2), WAIT_VM4(););
  }

  // ---- tail: tiles nt-2 (buf0), nt-1 (buf1) ----
  {
    const int kT = K - 64;  // last tile
    PH(READ_P1(Ard0, Brd0), STAGE(A, mBase + 128, kT, A11);, MQ32(0, 0), );
    PH(READ_P2(Ard0, Brd0), STAGE(B, nBase + 128, kT, B11);, MQ32(0, 2), );
    PH(READ_P3(Ard0),       ,                                MQ32(2, 0), );
    PH(,                    ,                                MQ32(2, 2), WAIT_VM0(););
    PH(READ_P1(Ard1, Brd1), ,                                MQ32(0, 0), );
    PH(READ_P2(Ard1, Brd1), ,                                MQ32(0, 2), );
    PH(READ_P3(Ard1),       ,                                MQ32(2, 0), );
    // final phase: no barrier needed after
    __builtin_amdgcn_s_setprio(1);
    MQ32(2, 2)
    __builtin_amdgcn_s_setprio(0);
  }

  // ---- epilogue: 32x32 C/D layout (m74/m101, rounds 3/11 verified):
  //      col = lane&31, row = (reg&3) + 8*(reg>>2) + 4*(lane>>5) ----
  const int cl = l & 31, ch = l >> 5;
  float* Cw = C + (size_t)(mBase + wm * 128 + 4 * ch) * N + nBase + wn * 64 + cl;
#pragma unroll
  for (int mi = 0; mi < 4; ++mi)
#pragma unroll
    for (int ni = 0; ni < 2; ++ni)
#pragma unroll
      for (int r = 0; r < 16; ++r)
        Cw[(size_t)(mi * 32 + (r & 3) + 8 * (r >> 2)) * N + ni * 32] =
            acc[mi][ni][r];
}

// ---- fallback (round-1 verified fused path; used only if ws too small) ----
typedef unsigned short ushort8f __attribute__((ext_vector_type(8)));
__global__ __launch_bounds__(256) void gemm_fb(
    const float* __restrict__ Af, const float* __restrict__ Wf,
    float* __restrict__ C, int M, int N, int K) {
  __shared__ __attribute__((aligned(16))) unsigned short Ash[128 * 64];
  __shared__ __attribute__((aligned(16))) unsigned short Bsh[128 * 64];
  const int t = threadIdx.x, l = t & 63, w = t >> 6;
  const int mBase = blockIdx.y * 128, nBase = blockIdx.x * 128;
  const int wm = w >> 1, wn = w & 1;
  const int lr = l & 15, lk = (l >> 4) * 8;
  f32x4 acc[4][4] = {};
  const int frow = t >> 1, fkh = (t & 1) * 32;
  for (int k0 = 0; k0 < K; k0 += 64) {
    const float* ga = Af + (size_t)(mBase + frow) * K + k0 + fkh;
    const float* gb = Wf + (size_t)(nBase + frow) * K + k0 + fkh;
#pragma unroll
    for (int j = 0; j < 4; ++j) {
      float4 a0 = reinterpret_cast<const float4*>(ga)[2 * j];
      float4 a1 = reinterpret_cast<const float4*>(ga)[2 * j + 1];
      float4 b0 = reinterpret_cast<const float4*>(gb)[2 * j];
      float4 b1 = reinterpret_cast<const float4*>(gb)[2 * j + 1];
      ushort8f oa = {f2bf(a0.x), f2bf(a0.y), f2bf(a0.z), f2bf(a0.w),
                     f2bf(a1.x), f2bf(a1.y), f2bf(a1.z), f2bf(a1.w)};
      ushort8f ob = {f2bf(b0.x), f2bf(b0.y), f2bf(b0.z), f2bf(b0.w),
                     f2bf(b1.x), f2bf(b1.y), f2bf(b1.z), f2bf(b1.w)};
      *reinterpret_cast<ushort8f*>(&Ash[frow * 64 + fkh + j * 8]) = oa;
      *reinterpret_cast<ushort8f*>(&Bsh[frow * 64 + fkh + j * 8]) = ob;
    }
    __syncthreads();
#pragma unroll
    for (int kk = 0; kk < 2; ++kk) {
      bf16x8 a[4], b[4];
#pragma unroll
      for (int mi = 0; mi < 4; ++mi)
        a[mi] = *reinterpret_cast<const bf16x8*>(
            &Ash[(wm * 64 + mi * 16 + lr) * 64 + kk * 32 + lk]);
#pragma unroll
      for (int ni = 0; ni < 4; ++ni)
        b[ni] = *reinterpret_cast<const bf16x8*>(
            &Bsh[(wn * 64 + ni * 16 + lr) * 64 + kk * 32 + lk]);
#pragma unroll
      for (int mi = 0; mi < 4; ++mi)
#pragma unroll
        for (int ni = 0; ni < 4; ++ni)
          acc[mi][ni] = __builtin_amdgcn_mfma_f32_16x16x32_bf16(
              a[mi], b[ni], acc[mi][ni], 0, 0, 0);
    }
    __syncthreads();
  }
  const int crow0 = mBase + wm * 64 + (l >> 4) * 4;
  const int ccol0 = nBase + wn * 64 + lr;
#pragma unroll
  for (int mi = 0; mi < 4; ++mi)
#pragma unroll
    for (int ni = 0; ni < 4; ++ni)
#pragma unroll
      for (int r = 0; r < 4; ++r)
        C[(size_t)(crow0 + mi * 16 + r) * N + ccol0 + ni * 16] =
            acc[mi][ni][r];
}

extern "C" void kernel_launch(void* const* d_in, const int* in_sizes, int n_in,
                              void* d_out, int out_size, void* d_ws, size_t ws_size,
                              hipStream_t stream) {
  (void)n_in; (void)out_size;
  const float* x = (const float*)d_in[0];
  const float* wgt = (const float*)d_in[1];
  float* out = (float*)d_out;

  const long x_elems = in_sizes[0];  // M*K
  const long w_elems = in_sizes[1];  // N*K
  const int K = 4096;
  const int M = (int)(x_elems / K);  // 8192
  const int N = (int)(w_elems / K);  // 4096

  const size_t need = (size_t)(x_elems + w_elems) * sizeof(unsigned short);
  const bool ok256 =
      (M % 256 == 0) && (N % 256 == 0) && (K % 128 == 0) && (K >= 256) &&
      ws_size >= need;
  if (ok256) {
    unsigned short* Abf = (unsigned short*)d_ws;
    unsigned short* Wbf = Abf + x_elems;
    cvt_f32_to_bf16<<<2048, 256, 0, stream>>>(x, Abf, x_elems / 4);
    cvt_f32_to_bf16<<<2048, 256, 0, stream>>>(wgt, Wbf, w_elems / 4);
    gemm256<<<dim3((M / 256) * (N / 256)), 512, 0, stream>>>(Abf, Wbf, out, M,
                                                             N, K);
  } else {
    dim3 grid(N / 128, M / 128);
    gemm_fb<<<grid, 256, 0, stream>>>(x, wgt, out, M, N, K);
  }
}

// Round 13
// 267.511 us; speedup vs baseline: 1.2176x; 1.0773x over previous
//
#include <hip/hip_runtime.h>
#include <hip/hip_bf16.h>
#include <stdint.h>

// out[M,N] = x[M,K] @ weight[N,K]^T ; M=8192, N=4096, K=4096, fp32 in/out.
// FINAL KERNEL (round 13 = revert to twice-verified best, rounds 5/10):
// Pass 1: fp32 -> bf16 convert (memory-bound, at roofline ~38us).
// Pass 2: 256x256 8-wave 8-phase bf16 16x16x32-MFMA GEMM, 227.7us = 1208 TF
//   (48% dense peak), MfmaUtil 55, SQ_LDS_BANK_CONFLICT 0, no spill.
// Structure: T1 bijective XCD swizzle; T2 both-sides LDS swizzle (linear
//   LDS dest for global_load_lds + inverse-swizzled global src + swizzled
//   ds_read); single end-of-phase barrier (waves drift within phase ->
//   LDS/MFMA pipes overlap across waves); compiler-counted lgkmcnt;
//   vmcnt(4)@P4/P8 (counted, never 0 mid-loop); T5 setprio around MFMA.
// Probes that did NOT beat this (round, result): 2-barrier lockstep
//   (r2 242us), read-hoist (r4 neutral), 4-phase merge (r6 +3us),
//   cross-barrier read pipeline (r8 spills 700us), kk-split (r9 neutral +
//   latent stage/read race), 32x32x16 shape (r3/r11/r12: 276/305/243us --
//   r12 conflict-free via bank-quad permutation, still loses: MFMA pipe is
//   not the binding resource). vmcnt depth provably maxed (drained loads
//   issued 2-5 phases earlier >> HBM latency).
// Schedule WAR/RAW audit (steady state):
//   P1: rd A0.lo+B0.lo | st A11 | MQ(0,0)   (Ard1 last read prev-P7)
//   P2: rd B0.hi       | st B11 | MQ(0,2)   (Brd1 last read prev-P6)
//   P3: rd A0.hi       | st B00 | MQ(4,0)   (Brd0 last read P2)
//   P4: -              | st A00 | MQ(4,2) VM4  (Ard0 last read P3)
//   P5-P8: buf1 mirror (st A01,B01,B10,A10), VM4@P8.
//   vmcnt(4)@P4 drains B10,A10,A11,B11 (buf1 complete) one barrier before
//   P5's first buf1 read; @P8 drains buf0 symmetrically.

typedef __bf16 bf16x8 __attribute__((ext_vector_type(8)));
typedef float f32x4 __attribute__((ext_vector_type(4)));

__device__ __forceinline__ unsigned short f2bf(float f) {
  unsigned u = __builtin_bit_cast(unsigned, f);
  u += 0x7FFFu + ((u >> 16) & 1u);  // RNE; Gaussian inputs, no NaN
  return (unsigned short)(u >> 16);
}

__global__ void cvt_f32_to_bf16(const float* __restrict__ src,
                                unsigned short* __restrict__ dst, long n4) {
  long i = (long)blockIdx.x * blockDim.x + threadIdx.x;
  const long stride = (long)gridDim.x * blockDim.x;
  for (; i < n4; i += stride) {
    float4 v = reinterpret_cast<const float4*>(src)[i];
    ushort4 o;
    o.x = f2bf(v.x); o.y = f2bf(v.y); o.z = f2bf(v.z); o.w = f2bf(v.w);
    reinterpret_cast<ushort4*>(dst)[i] = o;
  }
}

__device__ __forceinline__ void gload_lds16(const void* g, void* lds) {
  // async global->LDS, 16B/lane; LDS dest = wave-uniform base + lane*16
  __builtin_amdgcn_global_load_lds(
      (__attribute__((address_space(1))) void*)(g),
      (__attribute__((address_space(3))) void*)(lds), 16, 0, 0);
}

#define BARRIER()                                    \
  do {                                               \
    asm volatile("" ::: "memory");                   \
    __builtin_amdgcn_s_barrier();                    \
    asm volatile("" ::: "memory");                   \
  } while (0)
#define WAIT_VM4() asm volatile("s_waitcnt vmcnt(4)" ::: "memory")
#define WAIT_VM0() asm volatile("s_waitcnt vmcnt(0)" ::: "memory")

// ---- fragment read macros (compile-time indices only; rule #20) ----
#define READ_A(AB, LO)                                                      \
  _Pragma("unroll") for (int mi = 0; mi < 4; ++mi) {                        \
    const int row_ = ((LO)*4 + mi) * 16 + lr;                               \
    fa[(LO)*4 + mi][0] = *(const bf16x8*)((AB) + row_ * 128 + sx0);         \
    fa[(LO)*4 + mi][1] = *(const bf16x8*)((AB) + row_ * 128 + sx1);         \
  }
#define READ_B(BB, LO)                                                      \
  _Pragma("unroll") for (int ni = 0; ni < 2; ++ni) {                        \
    const int row_ = brow0 + ((LO)*2 + ni) * 16 + lr;                       \
    fb[(LO)*2 + ni][0] = *(const bf16x8*)((BB) + row_ * 128 + sx0);         \
    fb[(LO)*2 + ni][1] = *(const bf16x8*)((BB) + row_ * 128 + sx1);         \
  }
#define MQ(M0, N0)                                                          \
  _Pragma("unroll") for (int kk = 0; kk < 2; ++kk)                          \
  _Pragma("unroll") for (int mi = 0; mi < 4; ++mi)                          \
  _Pragma("unroll") for (int ni = 0; ni < 2; ++ni)                          \
      acc[(M0) + mi][(N0) + ni] = __builtin_amdgcn_mfma_f32_16x16x32_bf16(  \
          fa[(M0) + mi][kk], fb[(N0) + ni][kk], acc[(M0) + mi][(N0) + ni],  \
          0, 0, 0);

// phase: {reads || stage} -> prio1 MFMA prio0 -> [vm] -> barrier
// (no mid-phase barrier, no blanket lgkmcnt(0): compiler emits counted
//  lgkmcnt per consumer; waves drift within the phase and overlap pipes)
#define PH(READS, STAGES, M0, N0, WAITS)  \
  do {                                    \
    READS STAGES                          \
    __builtin_amdgcn_s_setprio(1);        \
    MQ(M0, N0)                            \
    __builtin_amdgcn_s_setprio(0);        \
    WAITS BARRIER();                      \
  } while (0)

__global__ __launch_bounds__(512, 2) void gemm256(
    const unsigned short* __restrict__ A, const unsigned short* __restrict__ B,
    float* __restrict__ C, int M, int N, int K) {
  // LDS: A halves at (buf*2+h)*16384 ; B at 65536 + (buf*2+h)*16384
  __shared__ __attribute__((aligned(1024))) char lds[131072];
  const int A00 = 0, A01 = 16384, A10 = 32768, A11 = 49152;
  const int B00 = 65536, B01 = 81920, B10 = 98304, B11 = 114688;

  const int t = threadIdx.x;
  const int l = t & 63;
  const int w = t >> 6;        // wave 0..7
  const int wm = w >> 2;       // 0..1 : 128-row half of the 256-row tile
  const int wn = w & 3;        // 0..3 : 64-col strip of the 256-col tile
  const int q = l >> 4;        // quarter-wave
  const int lr = l & 15;
  const int xc = (lr & 7) << 4;           // per-thread swizzle const
  const int sx0 = (q * 16) ^ xc;          // kk=0 slot byte (swizzled)
  const int sx1 = (64 + q * 16) ^ xc;     // kk=1 slot byte (swizzled)
  const int brow0 = (wn & 1) * 64;        // row offset inside B half
  const int srow = l >> 3;                // staging row within 8-row chunk
  const int sslot = ((l & 7) ^ ((l >> 3) & 7)) * 8;  // pre-swizzled src slot

  // T1: bijective XCD swizzle (nwg % 8 == 0 here)
  const int nwg = gridDim.x;
  int swz = blockIdx.x;
  if ((nwg & 7) == 0) swz = (swz & 7) * (nwg >> 3) + (swz >> 3);
  const int ntx = N >> 8;
  const int bx = swz % ntx;
  const int by = swz / ntx;
  const int mBase = by * 256, nBase = bx * 256;

  // read bases: wave's A half per buffer, B half per buffer
  const char* Ard0 = lds + wm * 16384;
  const char* Ard1 = lds + 32768 + wm * 16384;
  const char* Brd0 = lds + 65536 + (wn >> 1) * 16384;
  const char* Brd1 = lds + 98304 + (wn >> 1) * 16384;

  bf16x8 fa[8][2], fb[4][2];
  f32x4 acc[8][4] = {};

  auto STAGE = [&](const unsigned short* __restrict__ G, int row0, int k0,
                   int ldsOff) {
    const unsigned short* s =
        G + (size_t)(row0 + w * 8 + srow) * K + k0 + sslot;
    char* d = lds + ldsOff + w * 1024;
    gload_lds16(s, d);                          // rows 0-63 of the half
    gload_lds16(s + (size_t)64 * K, d + 8192);  // rows 64-127
  };

  // ---- prologue: tile0 (4 halves) + B10,A10 of tile1; drain tile0 ----
  STAGE(A, mBase, 0, A00);
  STAGE(A, mBase + 128, 0, A01);
  STAGE(B, nBase, 0, B00);
  STAGE(B, nBase + 128, 0, B01);
  STAGE(B, nBase, 64, B10);
  STAGE(A, mBase, 64, A10);
  WAIT_VM4();
  BARRIER();

  // ---- main loop: iteration i computes tiles 2i (buf0), 2i+1 (buf1) ----
  const int itermain = K / 128 - 1;
  for (int i = 0; i < itermain; ++i) {
    const int kA = (2 * i + 1) * 64;  // tile 2i+1
    const int kB = kA + 64;           // tile 2i+2
    const int kC = kB + 64;           // tile 2i+3
    PH(READ_A(Ard0, 0) READ_B(Brd0, 0), STAGE(A, mBase + 128, kA, A11);, 0, 0, );
    PH(READ_B(Brd0, 1),                 STAGE(B, nBase + 128, kA, B11);, 0, 2, );
    PH(READ_A(Ard0, 1),                 STAGE(B, nBase,       kB, B00);, 4, 0, );
    PH(,                                STAGE(A, mBase,       kB, A00);, 4, 2, WAIT_VM4(););
    PH(READ_A(Ard1, 0) READ_B(Brd1, 0), STAGE(A, mBase + 128, kB, A01);, 0, 0, );
    PH(READ_B(Brd1, 1),                 STAGE(B, nBase + 128, kB, B01);, 0, 2, );
    PH(READ_A(Ard1, 1),                 STAGE(B, nBase,       kC, B10);, 4, 0, );
    PH(,                                STAGE(A, mBase,       kC, A10);, 4, 2, WAIT_VM4(););
  }

  // ---- tail: tiles nt-2 (buf0), nt-1 (buf1) ----
  {
    const int kT = K - 64;  // last tile
    PH(READ_A(Ard0, 0) READ_B(Brd0, 0), STAGE(A, mBase + 128, kT, A11);, 0, 0, );
    PH(READ_B(Brd0, 1),                 STAGE(B, nBase + 128, kT, B11);, 0, 2, );
    PH(READ_A(Ard0, 1),                 ,                                4, 0, );
    PH(,                                ,                                4, 2, WAIT_VM0(););
    PH(READ_A(Ard1, 0) READ_B(Brd1, 0), ,                                0, 0, );
    PH(READ_B(Brd1, 1),                 ,                                0, 2, );
    PH(READ_A(Ard1, 1),                 ,                                4, 0, );
    PH(,                                ,                                4, 2, );
  }

  // ---- epilogue: C/D layout col=lane&15, row=(lane>>4)*4+reg (m89) ----
  float* Cw = C + (size_t)(mBase + wm * 128 + q * 4) * N + nBase + wn * 64 + lr;
#pragma unroll
  for (int mi = 0; mi < 8; ++mi)
#pragma unroll
    for (int ni = 0; ni < 4; ++ni)
#pragma unroll
      for (int r = 0; r < 4; ++r)
        Cw[(size_t)(mi * 16 + r) * N + ni * 16] = acc[mi][ni][r];
}

// ---- fallback (round-1 verified fused path; used only if ws too small) ----
typedef unsigned short ushort8f __attribute__((ext_vector_type(8)));
__global__ __launch_bounds__(256) void gemm_fb(
    const float* __restrict__ Af, const float* __restrict__ Wf,
    float* __restrict__ C, int M, int N, int K) {
  __shared__ __attribute__((aligned(16))) unsigned short Ash[128 * 64];
  __shared__ __attribute__((aligned(16))) unsigned short Bsh[128 * 64];
  const int t = threadIdx.x, l = t & 63, w = t >> 6;
  const int mBase = blockIdx.y * 128, nBase = blockIdx.x * 128;
  const int wm = w >> 1, wn = w & 1;
  const int lr = l & 15, lk = (l >> 4) * 8;
  f32x4 acc[4][4] = {};
  const int frow = t >> 1, fkh = (t & 1) * 32;
  for (int k0 = 0; k0 < K; k0 += 64) {
    const float* ga = Af + (size_t)(mBase + frow) * K + k0 + fkh;
    const float* gb = Wf + (size_t)(nBase + frow) * K + k0 + fkh;
#pragma unroll
    for (int j = 0; j < 4; ++j) {
      float4 a0 = reinterpret_cast<const float4*>(ga)[2 * j];
      float4 a1 = reinterpret_cast<const float4*>(ga)[2 * j + 1];
      float4 b0 = reinterpret_cast<const float4*>(gb)[2 * j];
      float4 b1 = reinterpret_cast<const float4*>(gb)[2 * j + 1];
      ushort8f oa = {f2bf(a0.x), f2bf(a0.y), f2bf(a0.z), f2bf(a0.w),
                     f2bf(a1.x), f2bf(a1.y), f2bf(a1.z), f2bf(a1.w)};
      ushort8f ob = {f2bf(b0.x), f2bf(b0.y), f2bf(b0.z), f2bf(b0.w),
                     f2bf(b1.x), f2bf(b1.y), f2bf(b1.z), f2bf(b1.w)};
      *reinterpret_cast<ushort8f*>(&Ash[frow * 64 + fkh + j * 8]) = oa;
      *reinterpret_cast<ushort8f*>(&Bsh[frow * 64 + fkh + j * 8]) = ob;
    }
    __syncthreads();
#pragma unroll
    for (int kk = 0; kk < 2; ++kk) {
      bf16x8 a[4], b[4];
#pragma unroll
      for (int mi = 0; mi < 4; ++mi)
        a[mi] = *reinterpret_cast<const bf16x8*>(
            &Ash[(wm * 64 + mi * 16 + lr) * 64 + kk * 32 + lk]);
#pragma unroll
      for (int ni = 0; ni < 4; ++ni)
        b[ni] = *reinterpret_cast<const bf16x8*>(
            &Bsh[(wn * 64 + ni * 16 + lr) * 64 + kk * 32 + lk]);
#pragma unroll
      for (int mi = 0; mi < 4; ++mi)
#pragma unroll
        for (int ni = 0; ni < 4; ++ni)
          acc[mi][ni] = __builtin_amdgcn_mfma_f32_16x16x32_bf16(
              a[mi], b[ni], acc[mi][ni], 0, 0, 0);
    }
    __syncthreads();
  }
  const int crow0 = mBase + wm * 64 + (l >> 4) * 4;
  const int ccol0 = nBase + wn * 64 + lr;
#pragma unroll
  for (int mi = 0; mi < 4; ++mi)
#pragma unroll
    for (int ni = 0; ni < 4; ++ni)
#pragma unroll
      for (int r = 0; r < 4; ++r)
        C[(size_t)(crow0 + mi * 16 + r) * N + ccol0 + ni * 16] =
            acc[mi][ni][r];
}

extern "C" void kernel_launch(void* const* d_in, const int* in_sizes, int n_in,
                              void* d_out, int out_size, void* d_ws, size_t ws_size,
                              hipStream_t stream) {
  (void)n_in; (void)out_size;
  const float* x = (const float*)d_in[0];
  const float* wgt = (const float*)d_in[1];
  float* out = (float*)d_out;

  const long x_elems = in_sizes[0];  // M*K
  const long w_elems = in_sizes[1];  // N*K
  const int K = 4096;
  const int M = (int)(x_elems / K);  // 8192
  const int N = (int)(w_elems / K);  // 4096

  const size_t need = (size_t)(x_elems + w_elems) * sizeof(unsigned short);
  const bool ok256 =
      (M % 256 == 0) && (N % 256 == 0) && (K % 128 == 0) && (K >= 256) &&
      ws_size >= need;
  if (ok256) {
    unsigned short* Abf = (unsigned short*)d_ws;
    unsigned short* Wbf = Abf + x_elems;
    cvt_f32_to_bf16<<<2048, 256, 0, stream>>>(x, Abf, x_elems / 4);
    cvt_f32_to_bf16<<<2048, 256, 0, stream>>>(wgt, Wbf, w_elems / 4);
    gemm256<<<dim3((M / 256) * (N / 256)), 512, 0, stream>>>(Abf, Wbf, out, M,
                                                             N, K);
  } else {
    dim3 grid(N / 128, M / 128);
    gemm_fb<<<grid, 256, 0, stream>>>(x, wgt, out, M, N, K);
  }
}